// Round 4
// baseline (192.926 us; speedup 1.0000x reference)
//
#include <hip/hip_runtime.h>

// Problem constants
#define BB 256      // batch
#define CCH 512     // channels
#define HW 196      // 14*14 spatial
#define TT 197      // templates_b rows (196 + 1 negative)
#define TROWS 208   // padded T rows (13 * 16)
#define TBK 224     // padded K for templates (7 * 32)

typedef __attribute__((ext_vector_type(8))) short bf16x8;
typedef __attribute__((ext_vector_type(4))) float f32x4;

__device__ __forceinline__ unsigned short f2bf(float f) {
    union { float f; unsigned u; } v; v.f = f;
    unsigned r = v.u + 0x7FFFu + ((v.u >> 16) & 1u);   // round-to-nearest-even
    return (unsigned short)(r >> 16);
}

// ---- prep: wgs 0..181 convert templates_b*tau -> bf16 zero-padded 208x224;
// wg 182 computes gmax = max(templates_f) (center peak is in every window,
// so max(sel) == max(templates_f) regardless of selection).
__global__ void prep(const float* __restrict__ tf, const float* __restrict__ tb,
                     float* __restrict__ wsf, unsigned short* __restrict__ tb_bf) {
    if (blockIdx.x < 182) {
        int i = blockIdx.x * 256 + threadIdx.x;     // 182*256 == 208*224 exactly
        int r = i / TBK, k = i % TBK;
        const float tau = 0.5f / 196.0f;
        float v = (r < TT && k < HW) ? tb[r * HW + k] * tau : 0.0f;
        tb_bf[i] = f2bf(v);
    } else {
        __shared__ float red[256];
        float m = -1e30f;
        for (int i = threadIdx.x; i < HW * HW; i += 256) m = fmaxf(m, tf[i]);
        red[threadIdx.x] = m;
        __syncthreads();
        for (int s = 128; s > 0; s >>= 1) {
            if (threadIdx.x < s) red[threadIdx.x] = fmaxf(red[threadIdx.x], red[threadIdx.x + s]);
            __syncthreads();
        }
        if (threadIdx.x == 0) wsf[0] = red[0];
    }
}

// ---- K_A: pure streaming. One thread-quad per (b,c) row; interleaved chunks
// q+4j so each quad covers one contiguous 64B segment per instruction.
// No LDS, no barriers; 2048 wgs of 256 threads.
extern "C" __global__ __launch_bounds__(256)
void stream_mask(const float* __restrict__ x, const float* __restrict__ tf,
                 const float* __restrict__ wsf,
                 float* __restrict__ xm_out, float* __restrict__ mask_out)
{
    const int tid = threadIdx.x;
    const int row = blockIdx.x * 64 + (tid >> 2);   // row = b*512 + c
    const int q   = tid & 3;
    const int nch = (q == 0) ? 13 : 12;             // q=0 also takes chunk 48
    const float rg = 1.0f / wsf[0];

    const size_t rowoff = (size_t)row * HW;
    const float* xrow = x + rowoff;

    f32x4 xv[13];
    #pragma unroll
    for (int j = 0; j < 13; ++j)
        if (j < nch) xv[j] = *(const f32x4*)(xrow + (q + 4 * j) * 4);

    float bv = -1e30f; int bi = 0;
    #pragma unroll
    for (int j = 0; j < 13; ++j) if (j < nch) {
        #pragma unroll
        for (int e = 0; e < 4; ++e) {
            float v = xv[j][e];
            int k = (q + 4 * j) * 4 + e;
            if (v > bv) { bv = v; bi = k; }         // k ascends per lane -> first max kept
        }
    }
    #pragma unroll
    for (int m = 1; m <= 2; m <<= 1) {
        float ov = __shfl_xor(bv, m, 64);
        int   oi = __shfl_xor(bi, m, 64);
        if (ov > bv || (ov == bv && oi < bi)) { bv = ov; bi = oi; }
    }

    const float* selrow = tf + (size_t)bi * HW;
    float* xmrow = xm_out + rowoff;
    float* mkrow = mask_out + rowoff;

    #pragma unroll
    for (int j = 0; j < 13; ++j) if (j < nch) {
        const int k0 = (q + 4 * j) * 4;
        f32x4 sel = *(const f32x4*)(selrow + k0);
        f32x4 mk, xm;
        #pragma unroll
        for (int e = 0; e < 4; ++e) {
            float m = fmaxf(sel[e] * rg - 0.2f, 0.0f) * 5.0f;
            mk[e] = m;
            xm[e] = xv[j][e] * m;
        }
        *(f32x4*)(xmrow + k0) = xm;
        *(f32x4*)(mkrow + k0) = mk;
    }
}

// ---- K_B: per-channel GEMM + softmax + MI loss. 512 wgs x 1024 thr (16 waves).
// Wave w owns batch cols w*16..w*16+15; all 13 M-tiles of tr in registers.
// B-frags: read xm fp32 from d_out (L3-hot), convert to bf16 in-register.
// A-frags: direct from tb_bf global (93 KB; wg-uniform addresses -> L1-served).
extern "C" __global__ __launch_bounds__(1024)
void gemm_loss(const float* __restrict__ xm, const unsigned short* __restrict__ tb_bf,
               const float* __restrict__ pT, float* __restrict__ loss_out)
{
    __shared__ float s_part[16 * TROWS];
    __shared__ float rAs[TROWS];
    __shared__ float pTs[TROWS];
    __shared__ float red[16];

    const int c    = blockIdx.x;
    const int tid  = threadIdx.x;
    const int lane = tid & 63;
    const int w    = tid >> 6;
    const int l15  = lane & 15, lg = lane >> 4;

    if (tid < TROWS) pTs[tid] = (tid < TT) ? pT[tid] : 0.0f;

    const int b = w * 16 + l15;
    const float* xrow = xm + ((size_t)b * CCH + c) * HW;

    f32x4 acc[13];
    #pragma unroll
    for (int mt = 0; mt < 13; ++mt) acc[mt] = (f32x4){0.f, 0.f, 0.f, 0.f};

    #pragma unroll 1
    for (int kt = 0; kt < 6; ++kt) {
        const int k0 = kt * 32 + lg * 8;
        f32x4 u0 = *(const f32x4*)(xrow + k0);
        f32x4 u1 = *(const f32x4*)(xrow + k0 + 4);
        bf16x8 bfrag;
        #pragma unroll
        for (int e = 0; e < 4; ++e) {
            bfrag[e]     = (short)f2bf(u0[e]);
            bfrag[e + 4] = (short)f2bf(u1[e]);
        }
        #pragma unroll
        for (int mt = 0; mt < 13; ++mt) {
            bf16x8 afrag = *(const bf16x8*)(tb_bf + (mt * 16 + l15) * TBK + k0);
            acc[mt] = __builtin_amdgcn_mfma_f32_16x16x32_bf16(afrag, bfrag, acc[mt], 0, 0, 0);
        }
    }
    {   // tail kt=6: k 192..223, only k<196 real (lg==0 elems 0..3)
        const int k0 = 192 + lg * 8;
        bf16x8 bfrag = (bf16x8){0, 0, 0, 0, 0, 0, 0, 0};
        if (lg == 0) {
            f32x4 u0 = *(const f32x4*)(xrow + 192);
            #pragma unroll
            for (int e = 0; e < 4; ++e) bfrag[e] = (short)f2bf(u0[e]);
        }
        #pragma unroll
        for (int mt = 0; mt < 13; ++mt) {
            bf16x8 afrag = *(const bf16x8*)(tb_bf + (mt * 16 + l15) * TBK + k0);
            acc[mt] = __builtin_amdgcn_mfma_f32_16x16x32_bf16(afrag, bfrag, acc[mt], 0, 0, 0);
        }
    }

    // ---- Phase A: exp in-register, column-sum over this wave's 16 b, cross-wave via LDS
    float* sp = s_part + w * TROWS;
    #pragma unroll
    for (int mt = 0; mt < 13; ++mt) {
        #pragma unroll
        for (int e = 0; e < 4; ++e) acc[mt][e] = __expf(acc[mt][e]);
        f32x4 s = acc[mt];
        #pragma unroll
        for (int m = 1; m <= 8; m <<= 1) {
            #pragma unroll
            for (int e = 0; e < 4; ++e) s[e] += __shfl_xor(s[e], m, 64);
        }
        if (l15 == 0) *(f32x4*)(sp + mt * 16 + lg * 4) = s;
    }
    __syncthreads();
    if (tid < TROWS) {
        float s = 0.f;
        #pragma unroll
        for (int w2 = 0; w2 < 16; ++w2) s += s_part[w2 * TROWS + tid];
        rAs[tid] = 1.0f / s;
    }
    __syncthreads();

    // ---- Phase B: p = exp*rA, px[b] = sum_t pT*p
    float px = 0.f;
    #pragma unroll
    for (int mt = 0; mt < 13; ++mt) {
        const int t0 = mt * 16 + lg * 4;
        f32x4 ra = *(const f32x4*)(rAs + t0);
        f32x4 pt = *(const f32x4*)(pTs + t0);
        #pragma unroll
        for (int e = 0; e < 4; ++e) {
            float p = acc[mt][e] * ra[e];
            acc[mt][e] = p;
            px += pt[e] * p;
        }
    }
    px += __shfl_xor(px, 16, 64);
    px += __shfl_xor(px, 32, 64);
    const float rpx = 1.0f / px;

    // ---- Phase C: loss partial = sum_t pT * p * log(p/px)
    float part = 0.f;
    #pragma unroll
    for (int mt = 0; mt < 13; ++mt) {
        const int t0 = mt * 16 + lg * 4;
        f32x4 pt = *(const f32x4*)(pTs + t0);
        #pragma unroll
        for (int e = 0; e < 4; ++e) {
            float p = acc[mt][e];
            part += pt[e] * p * __logf(p * rpx);
        }
    }
    #pragma unroll
    for (int off = 32; off >= 1; off >>= 1) part += __shfl_xor(part, off, 64);
    if (lane == 0) red[w] = part;
    __syncthreads();
    if (tid == 0) {
        float s = 0.f;
        #pragma unroll
        for (int w2 = 0; w2 < 16; ++w2) s += red[w2];
        loss_out[c] = -s;
    }
}

extern "C" void kernel_launch(void* const* d_in, const int* in_sizes, int n_in,
                              void* d_out, int out_size, void* d_ws, size_t ws_size,
                              hipStream_t stream) {
    const float* x  = (const float*)d_in[0];
    const float* tf = (const float*)d_in[1];
    const float* tb = (const float*)d_in[2];
    const float* pT = (const float*)d_in[3];

    const size_t NOUT = (size_t)BB * CCH * HW;
    float* xm_out = (float*)d_out;
    float* mk_out = xm_out + NOUT;
    float* ls_out = mk_out + NOUT;

    float* wsf = (float*)d_ws;
    unsigned short* tb_bf = (unsigned short*)((char*)d_ws + 64);   // 208*224*2 = 93184 B

    prep<<<183, 256, 0, stream>>>(tf, tb, wsf, tb_bf);
    stream_mask<<<2048, 256, 0, stream>>>(x, tf, wsf, xm_out, mk_out);
    gemm_loss<<<CCH, 1024, 0, stream>>>(xm_out, tb_bf, pT, ls_out);
}

// Round 5
// 187.012 us; speedup vs baseline: 1.0316x; 1.0316x over previous
//
#include <hip/hip_runtime.h>

// Problem constants
#define BB 256      // batch
#define CCH 512     // channels
#define HW 196      // 14*14 spatial
#define TT 197      // templates_b rows (196 + 1 negative)
#define TROWS 208   // padded T rows (13 * 16)
#define TBK 224     // padded K for templates (7 * 32)

typedef __attribute__((ext_vector_type(8))) short bf16x8;
typedef __attribute__((ext_vector_type(4))) float f32x4;

__device__ __forceinline__ unsigned short f2bf(float f) {
    union { float f; unsigned u; } v; v.f = f;
    unsigned r = v.u + 0x7FFFu + ((v.u >> 16) & 1u);   // round-to-nearest-even
    return (unsigned short)(r >> 16);
}

// ---- prep: wgs 0..181 convert templates_b*tau -> bf16 zero-padded 208x224;
// wg 182 computes gmax = max(templates_f) (the base's center peak is inside
// every 14x14 window, so max(sel) == max(templates_f) for any selection).
__global__ void prep(const float* __restrict__ tf, const float* __restrict__ tb,
                     float* __restrict__ wsf, unsigned short* __restrict__ tb_bf) {
    if (blockIdx.x < 182) {
        int i = blockIdx.x * 256 + threadIdx.x;     // 182*256 == 208*224 exactly
        int r = i / TBK, k = i % TBK;
        const float tau = 0.5f / 196.0f;
        float v = (r < TT && k < HW) ? tb[r * HW + k] * tau : 0.0f;
        tb_bf[i] = f2bf(v);
    } else {
        __shared__ float red[256];
        float m = -1e30f;
        for (int i = threadIdx.x; i < HW * HW; i += 256) m = fmaxf(m, tf[i]);
        red[threadIdx.x] = m;
        __syncthreads();
        for (int s = 128; s > 0; s >>= 1) {
            if (threadIdx.x < s) red[threadIdx.x] = fmaxf(red[threadIdx.x], red[threadIdx.x + s]);
            __syncthreads();
        }
        if (threadIdx.x == 0) wsf[0] = red[0];
    }
}

// ---- fused kernel: one wg (1024 thr, 16 waves) per channel, NO LDS data tile.
// Wave w stages its own 16 batch rows straight into B-fragment registers:
// lane (l15,lg) owns row b=w*16+l15, chunks kt*8+2*lg+{0,1} (k = kt*32+lg*8..+7)
// == exactly the mfma_16x16x32 B-frag layout. No stage->GEMM barrier; only the
// two softmax reductions synchronize waves.
extern "C" __global__ __launch_bounds__(1024)
void fused_one(const float* __restrict__ x, const float* __restrict__ tf,
               const float* __restrict__ pT, const unsigned short* __restrict__ tb_bf,
               const float* __restrict__ wsf,
               float* __restrict__ xm_out, float* __restrict__ mask_out,
               float* __restrict__ loss_out)
{
    __shared__ float s_part[16 * TROWS];
    __shared__ float rAs[TROWS];
    __shared__ float pTs[TROWS];
    __shared__ float red[16];

    const int c    = blockIdx.x;
    const int tid  = threadIdx.x;
    const int lane = tid & 63;
    const int w    = tid >> 6;
    const int l15  = lane & 15, lg = lane >> 4;
    const float rg = 1.0f / wsf[0];

    if (tid < TROWS) pTs[tid] = (tid < TT) ? pT[tid] : 0.0f;

    const int b = w * 16 + l15;
    const size_t rowoff = ((size_t)b * CCH + c) * HW;
    const float* xrow = x + rowoff;

    // ---- load this lane's 12 (13 for lg==0) chunks of its row
    f32x4 u[13];
    #pragma unroll
    for (int kt = 0; kt < 6; ++kt) {
        u[2 * kt]     = *(const f32x4*)(xrow + kt * 32 + lg * 8);
        u[2 * kt + 1] = *(const f32x4*)(xrow + kt * 32 + lg * 8 + 4);
    }
    if (lg == 0) u[12] = *(const f32x4*)(xrow + 192);
    else         u[12] = (f32x4){-__builtin_inff(), -__builtin_inff(),
                                 -__builtin_inff(), -__builtin_inff()};

    // ---- argmax (k ascends within each lane's scan -> strict > keeps first)
    float bv = -__builtin_inff(); int bi = 0;
    #pragma unroll
    for (int j = 0; j < 13; ++j) {
        const int k0 = (j < 12) ? (((j >> 1) * 8 + lg * 2 + (j & 1)) * 4) : 192;
        #pragma unroll
        for (int e = 0; e < 4; ++e) {
            float v = u[j][e];
            if (v > bv) { bv = v; bi = k0 + e; }
        }
    }
    #pragma unroll
    for (int m = 16; m <= 32; m <<= 1) {   // reduce over lg (lanes l15+16g)
        float ov = __shfl_xor(bv, m, 64);
        int   oi = __shfl_xor(bi, m, 64);
        if (ov > bv || (ov == bv && oi < bi)) { bv = ov; bi = oi; }
    }

    // ---- mask, outputs, and B-frag pack (u dies into fr)
    const float* selrow = tf + (size_t)bi * HW;
    float* xmrow = xm_out + rowoff;
    float* mkrow = mask_out + rowoff;
    bf16x8 fr[7];

    #pragma unroll
    for (int kt = 0; kt < 6; ++kt) {
        #pragma unroll
        for (int h = 0; h < 2; ++h) {
            const int k0 = kt * 32 + lg * 8 + h * 4;
            f32x4 sel = *(const f32x4*)(selrow + k0);
            f32x4 mk, xm;
            #pragma unroll
            for (int e = 0; e < 4; ++e) {
                float m = fmaxf(sel[e] * rg - 0.2f, 0.0f) * 5.0f;
                mk[e] = m;
                xm[e] = u[2 * kt + h][e] * m;
            }
            *(f32x4*)(xmrow + k0) = xm;
            *(f32x4*)(mkrow + k0) = mk;
            #pragma unroll
            for (int e = 0; e < 4; ++e) fr[kt][h * 4 + e] = (short)f2bf(xm[e]);
        }
    }
    {   // kt=6: only lg==0 has real data (floats 192..195); rest zero-pad
        fr[6] = (bf16x8){0, 0, 0, 0, 0, 0, 0, 0};
        if (lg == 0) {
            f32x4 sel = *(const f32x4*)(selrow + 192);
            f32x4 mk, xm;
            #pragma unroll
            for (int e = 0; e < 4; ++e) {
                float m = fmaxf(sel[e] * rg - 0.2f, 0.0f) * 5.0f;
                mk[e] = m;
                xm[e] = u[12][e] * m;
            }
            *(f32x4*)(xmrow + 192) = xm;
            *(f32x4*)(mkrow + 192) = mk;
            #pragma unroll
            for (int e = 0; e < 4; ++e) fr[6][e] = (short)f2bf(xm[e]);
        }
    }

    // ---- GEMM: tr[t = mt*16+lg*4+e][b = w*16+l15], A-frags streamed from L2
    f32x4 acc[13];
    #pragma unroll
    for (int mt = 0; mt < 13; ++mt) acc[mt] = (f32x4){0.f, 0.f, 0.f, 0.f};

    #pragma unroll
    for (int kt = 0; kt < 7; ++kt) {
        const int kb = kt * 32 + lg * 8;
        const bf16x8 bfrag = fr[kt];
        #pragma unroll
        for (int mt = 0; mt < 13; ++mt) {
            bf16x8 afrag = *(const bf16x8*)(tb_bf + (mt * 16 + l15) * TBK + kb);
            acc[mt] = __builtin_amdgcn_mfma_f32_16x16x32_bf16(afrag, bfrag, acc[mt], 0, 0, 0);
        }
    }

    // ---- Phase A: exp in-register, col-sum over this wave's 16 b, cross-wave via LDS
    float* sp = s_part + w * TROWS;
    #pragma unroll
    for (int mt = 0; mt < 13; ++mt) {
        #pragma unroll
        for (int e = 0; e < 4; ++e) acc[mt][e] = __expf(acc[mt][e]);
        f32x4 s = acc[mt];
        #pragma unroll
        for (int m = 1; m <= 8; m <<= 1) {
            #pragma unroll
            for (int e = 0; e < 4; ++e) s[e] += __shfl_xor(s[e], m, 64);
        }
        if (l15 == 0) *(f32x4*)(sp + mt * 16 + lg * 4) = s;
    }
    __syncthreads();
    if (tid < TROWS) {
        float s = 0.f;
        #pragma unroll
        for (int w2 = 0; w2 < 16; ++w2) s += s_part[w2 * TROWS + tid];
        rAs[tid] = 1.0f / s;
    }
    __syncthreads();

    // ---- Phase B: p = exp*rA, px[b] = sum_t pT*p
    float px = 0.f;
    #pragma unroll
    for (int mt = 0; mt < 13; ++mt) {
        const int t0 = mt * 16 + lg * 4;
        f32x4 ra = *(const f32x4*)(rAs + t0);
        f32x4 pt = *(const f32x4*)(pTs + t0);
        #pragma unroll
        for (int e = 0; e < 4; ++e) {
            float p = acc[mt][e] * ra[e];
            acc[mt][e] = p;
            px += pt[e] * p;
        }
    }
    px += __shfl_xor(px, 16, 64);
    px += __shfl_xor(px, 32, 64);
    const float rpx = 1.0f / px;

    // ---- Phase C: loss partial = sum_t pT * p * log(p/px)
    float part = 0.f;
    #pragma unroll
    for (int mt = 0; mt < 13; ++mt) {
        const int t0 = mt * 16 + lg * 4;
        f32x4 pt = *(const f32x4*)(pTs + t0);
        #pragma unroll
        for (int e = 0; e < 4; ++e) {
            float p = acc[mt][e];
            part += pt[e] * p * __logf(p * rpx);
        }
    }
    #pragma unroll
    for (int off = 32; off >= 1; off >>= 1) part += __shfl_xor(part, off, 64);
    if (lane == 0) red[w] = part;
    __syncthreads();
    if (tid == 0) {
        float s = 0.f;
        #pragma unroll
        for (int w2 = 0; w2 < 16; ++w2) s += red[w2];
        loss_out[c] = -s;
    }
}

extern "C" void kernel_launch(void* const* d_in, const int* in_sizes, int n_in,
                              void* d_out, int out_size, void* d_ws, size_t ws_size,
                              hipStream_t stream) {
    const float* x  = (const float*)d_in[0];
    const float* tf = (const float*)d_in[1];
    const float* tb = (const float*)d_in[2];
    const float* pT = (const float*)d_in[3];

    const size_t NOUT = (size_t)BB * CCH * HW;
    float* xm_out = (float*)d_out;
    float* mk_out = xm_out + NOUT;
    float* ls_out = mk_out + NOUT;

    float* wsf = (float*)d_ws;
    unsigned short* tb_bf = (unsigned short*)((char*)d_ws + 64);   // 208*224*2 = 93184 B

    prep<<<183, 256, 0, stream>>>(tf, tb, wsf, tb_bf);
    fused_one<<<CCH, 1024, 0, stream>>>(x, tf, pT, tb_bf, wsf, xm_out, mk_out, ls_out);
}